// Round 4
// baseline (587.206 us; speedup 1.0000x reference)
//
#include <hip/hip_runtime.h>
#include <hip/hip_bf16.h>
#include <math.h>

#define DIM   1024
#define NEXP  8
#define HID   1536
#define NTOK  8192
#define NPOS  16384   // NTOK * TOP_K
#define PADR  128     // padding rows for tile overrun reads

typedef __attribute__((ext_vector_type(8))) short bf16x8;
typedef __attribute__((ext_vector_type(4))) float floatx4;

__device__ __forceinline__ unsigned short f2bf(float f) {
  unsigned int u = __float_as_uint(f);
  u += 0x7FFFu + ((u >> 16) & 1u);   // round-to-nearest-even
  return (unsigned short)(u >> 16);
}

__device__ __forceinline__ float bf2f(unsigned short h) {
  return __uint_as_float((unsigned int)h << 16);
}

__device__ __forceinline__ void async_cp16(void* lds, const void* g) {
  __builtin_amdgcn_global_load_lds(
      (const __attribute__((address_space(1))) unsigned int*)g,
      (__attribute__((address_space(3))) unsigned int*)lds, 16, 0, 0);
}

// count + exclusive-prefix offset for expert e, from hdr[0..7]
__device__ __forceinline__ int2 cnt_off(const int* __restrict__ hdr, int e) {
  int s = 0, c = 0;
#pragma unroll
  for (int i = 0; i < NEXP; ++i) {
    const int v = hdr[i];
    if (i < e) s += v;
    if (i == e) c = v;
  }
  return make_int2(c, s);
}

// ---------------- router: logits, top-2, softmax (no atomics) --------------
__global__ __launch_bounds__(256) void moe_router(
    const float* __restrict__ x, const float* __restrict__ Wr,
    int* __restrict__ meta_e, float* __restrict__ meta_w) {
  const int wave = threadIdx.x >> 6, lane = threadIdx.x & 63;
  const int token = blockIdx.x * 4 + wave;
  const float* xr = x + (size_t)token * DIM;
  float acc[NEXP];
#pragma unroll
  for (int e = 0; e < NEXP; ++e) acc[e] = 0.f;
  for (int i = lane; i < DIM; i += 64) {
    const float xv = xr[i];
    const float* wr = Wr + (size_t)i * NEXP;
#pragma unroll
    for (int e = 0; e < NEXP; ++e) acc[e] += xv * wr[e];
  }
#pragma unroll
  for (int off = 32; off > 0; off >>= 1) {
#pragma unroll
    for (int e = 0; e < NEXP; ++e) acc[e] += __shfl_down(acc[e], off);
  }
  if (lane == 0) {
    int i0 = 0; float v0 = acc[0];
#pragma unroll
    for (int e = 1; e < NEXP; ++e) if (acc[e] > v0) { v0 = acc[e]; i0 = e; }
    int i1 = -1; float v1 = -3.4e38f;
#pragma unroll
    for (int e = 0; e < NEXP; ++e) if (e != i0 && acc[e] > v1) { v1 = acc[e]; i1 = e; }
    const float w0 = 1.f / (1.f + expf(v1 - v0));  // stable softmax over top-2
    meta_e[token * 2 + 0] = i0;
    meta_e[token * 2 + 1] = i1;
    meta_w[token * 2 + 0] = w0;
    meta_w[token * 2 + 1] = 1.f - w0;
  }
}

// ------------- histogram: wave-aggregated counts into hdr[0..7] ------------
__global__ __launch_bounds__(256) void moe_hist(
    const int* __restrict__ meta_e, int* __restrict__ hdr) {
  const int idx = blockIdx.x * 256 + threadIdx.x;  // over NPOS entries
  const int lane = threadIdx.x & 63;
  const int e = meta_e[idx];
#pragma unroll
  for (int ex = 0; ex < NEXP; ++ex) {
    const unsigned long long m = __ballot(e == ex);
    if (m && lane == 0) atomicAdd(&hdr[ex], __popcll(m));
  }
}

// -------- build permutation + inverse map, wave-aggregated cursors ---------
// hdr[16..23] = cursors
__global__ __launch_bounds__(256) void moe_build(
    const int* __restrict__ meta_e, int* __restrict__ hdr,
    int* __restrict__ tok, int* __restrict__ inv) {
  const int idx = blockIdx.x * 256 + threadIdx.x;  // over NPOS entries
  const int lane = threadIdx.x & 63;
  const int token = idx >> 1;
  const int e = meta_e[idx];
  int pos = 0;
#pragma unroll
  for (int ex = 0; ex < NEXP; ++ex) {
    const unsigned long long m = __ballot(e == ex);
    if (m) {
      const int leader = (int)__ffsll((long long)m) - 1;
      int base = 0;
      if (lane == leader) base = atomicAdd(&hdr[16 + ex], __popcll(m));
      base = __shfl(base, leader);
      if (e == ex) {
        const int2 co = cnt_off(hdr, ex);
        pos = co.y + base + (int)__popcll(m & ((1ull << lane) - 1ull));
      }
    }
  }
  tok[pos] = token;
  inv[idx] = pos;
}

// ---------------- gather x rows into bf16, expert-grouped ------------------
__global__ __launch_bounds__(256) void moe_gather(
    const float* __restrict__ x, const int* __restrict__ tok,
    unsigned short* __restrict__ Xg) {
  const int pos = blockIdx.x;
  const int t = tok[pos];
  const float4 v = ((const float4*)(x + (size_t)t * DIM))[threadIdx.x];
  ushort4 o = make_ushort4(f2bf(v.x), f2bf(v.y), f2bf(v.z), f2bf(v.w));
  ((ushort4*)(Xg + (size_t)pos * DIM))[threadIdx.x] = o;
}

// ---------- fused fp32 [E][R][C] -> bf16 [E][C][R] transpose (all 3) -------
// 64x64 tiles: float4 loads, ushort4 stores. tile stride 65 -> 2-way LDS max.
__global__ __launch_bounds__(256) void moe_transpose_all(
    const float* __restrict__ W1, const float* __restrict__ W3,
    const float* __restrict__ W2,
    unsigned short* __restrict__ W1t, unsigned short* __restrict__ W3t,
    unsigned short* __restrict__ W2t) {
  __shared__ float tile[64][65];
  const int z = blockIdx.z;
  const int which = z >> 3, e = z & 7;
  const float* src; unsigned short* dst; int R, C;
  if (which == 0)      { src = W1; dst = W1t; R = DIM; C = HID; }
  else if (which == 1) { src = W3; dst = W3t; R = DIM; C = HID; }
  else                 { src = W2; dst = W2t; R = HID; C = DIM; }
  const int nbx = C / 64;
  const int bx = blockIdx.x % nbx, by = blockIdx.x / nbx;
  const float* ein = src + (size_t)e * R * C;
  unsigned short* eout = dst + (size_t)e * R * C;
  const int c0 = bx * 64, r0 = by * 64;
  const int lx = threadIdx.x & 15, ly = threadIdx.x >> 4;
#pragma unroll
  for (int it = 0; it < 4; ++it) {
    const int r = ly + it * 16;
    const float4 v = *(const float4*)&ein[(size_t)(r0 + r) * C + c0 + lx * 4];
    tile[r][lx * 4 + 0] = v.x;
    tile[r][lx * 4 + 1] = v.y;
    tile[r][lx * 4 + 2] = v.z;
    tile[r][lx * 4 + 3] = v.w;
  }
  __syncthreads();
#pragma unroll
  for (int it = 0; it < 4; ++it) {
    const int cc = ly + it * 16;
    ushort4 o = make_ushort4(f2bf(tile[lx * 4 + 0][cc]), f2bf(tile[lx * 4 + 1][cc]),
                             f2bf(tile[lx * 4 + 2][cc]), f2bf(tile[lx * 4 + 3][cc]));
    *(ushort4*)&eout[(size_t)(c0 + cc) * R + r0 + lx * 4] = o;
  }
}

// ---------------- GEMM1: Hbuf = silu(Xg@W1) * (Xg@W3), grouped -------------
// 128x64 tile, BK=64 (32 MFMA per barrier), dual-B fused. 4 waves as 2x2.
__global__ __launch_bounds__(256) void moe_gemm1(
    const unsigned short* __restrict__ Xg,
    const unsigned short* __restrict__ W1t,
    const unsigned short* __restrict__ W3t,
    unsigned short* __restrict__ Hbuf,
    const int* __restrict__ hdr) {
  const int e = blockIdx.y;
  const int NT = HID / 64;  // 24
  const int tileRow = blockIdx.x / NT;
  const int tileN = blockIdx.x % NT;
  const int2 co = cnt_off(hdr, e);
  const int cnt = co.x;
  if (tileRow * 128 >= cnt) return;
  const int off = co.y;
  const size_t tileM = (size_t)off + (size_t)tileRow * 128;
  const int n0 = tileN * 64;

  __shared__ unsigned short As[128 * 64];   // 16 KB
  __shared__ unsigned short B1s[64 * 64];   // 8 KB
  __shared__ unsigned short B3s[64 * 64];   // 8 KB

  const int lane = threadIdx.x & 63;
  const int wave = threadIdx.x >> 6;
  const int wm = wave >> 1, wn = wave & 1;
  const int rsub8 = lane >> 3;        // row within 8-row staging chunk
  const int ksub8 = (lane & 7) * 8;   // k-short offset within 64-wide row

  const unsigned short* Abase = Xg + tileM * DIM;
  const unsigned short* B1base = W1t + ((size_t)e * HID + n0) * DIM;
  const unsigned short* B3base = W3t + ((size_t)e * HID + n0) * DIM;

  floatx4 zero = {0.f, 0.f, 0.f, 0.f};
  floatx4 acc_h[4][2], acc_g[4][2];
#pragma unroll
  for (int i = 0; i < 4; ++i)
#pragma unroll
    for (int j = 0; j < 2; ++j) { acc_h[i][j] = zero; acc_g[i][j] = zero; }

  for (int k0 = 0; k0 < DIM; k0 += 64) {
    // A: 16 chunks of 8 rows (1 KB each); wave stages 4
#pragma unroll
    for (int t = 0; t < 4; ++t) {
      const int c = wave * 4 + t;
      const int row = c * 8 + rsub8;
      async_cp16(&As[c * 512], Abase + (size_t)row * DIM + k0 + ksub8);
    }
    // B1/B3: 8 chunks each; wave stages 2 of each
#pragma unroll
    for (int t = 0; t < 2; ++t) {
      const int c = wave * 2 + t;
      const int row = c * 8 + rsub8;
      async_cp16(&B1s[c * 512], B1base + (size_t)row * DIM + k0 + ksub8);
      async_cp16(&B3s[c * 512], B3base + (size_t)row * DIM + k0 + ksub8);
    }
    __syncthreads();
#pragma unroll
    for (int s = 0; s < 2; ++s) {
      bf16x8 a[4], b1[2], b3[2];
      const int ko = s * 32 + (lane >> 4) * 8;
#pragma unroll
      for (int i = 0; i < 4; ++i)
        a[i] = *(const bf16x8*)&As[(wm * 64 + i * 16 + (lane & 15)) * 64 + ko];
#pragma unroll
      for (int j = 0; j < 2; ++j) {
        b1[j] = *(const bf16x8*)&B1s[(wn * 32 + j * 16 + (lane & 15)) * 64 + ko];
        b3[j] = *(const bf16x8*)&B3s[(wn * 32 + j * 16 + (lane & 15)) * 64 + ko];
      }
#pragma unroll
      for (int i = 0; i < 4; ++i)
#pragma unroll
        for (int j = 0; j < 2; ++j) {
          acc_h[i][j] = __builtin_amdgcn_mfma_f32_16x16x32_bf16(a[i], b1[j], acc_h[i][j], 0, 0, 0);
          acc_g[i][j] = __builtin_amdgcn_mfma_f32_16x16x32_bf16(a[i], b3[j], acc_g[i][j], 0, 0, 0);
        }
    }
    __syncthreads();
  }

  // epilogue: silu(h)*g -> bf16, guarded against tile overrun into next expert
  const int r0 = (lane >> 4) * 4;
  const int cc = lane & 15;
#pragma unroll
  for (int i = 0; i < 4; ++i)
#pragma unroll
    for (int r = 0; r < 4; ++r) {
      const int lrow = tileRow * 128 + wm * 64 + i * 16 + r0 + r;
      if (lrow < cnt) {
        unsigned short* hrow = Hbuf + (size_t)(off + lrow) * HID + n0 + wn * 32 + cc;
#pragma unroll
        for (int j = 0; j < 2; ++j) {
          const float h = acc_h[i][j][r];
          const float g = acc_g[i][j][r];
          const float s = h / (1.f + expf(-h));
          hrow[j * 16] = f2bf(s * g);
        }
      }
    }
}

// ---------------- GEMM2: Y[pos] = Hbuf @ W2 (bf16 rows, no atomics) --------
// 128x64 tile, BK=64. A: Hbuf [pos][k] (k=HID). B: W2t [E][n][k] (n over DIM).
__global__ __launch_bounds__(256) void moe_gemm2(
    const unsigned short* __restrict__ Hbuf,
    const unsigned short* __restrict__ W2t,
    const int* __restrict__ hdr,
    unsigned short* __restrict__ Y) {
  const int e = blockIdx.y;
  const int NT = DIM / 64;  // 16
  const int tileRow = blockIdx.x / NT;
  const int tileN = blockIdx.x % NT;
  const int2 co = cnt_off(hdr, e);
  const int cnt = co.x;
  if (tileRow * 128 >= cnt) return;
  const int off = co.y;
  const size_t tileM = (size_t)off + (size_t)tileRow * 128;
  const int n0 = tileN * 64;

  __shared__ unsigned short As[128 * 64];   // 16 KB
  __shared__ unsigned short Bs[64 * 64];    // 8 KB

  const int lane = threadIdx.x & 63;
  const int wave = threadIdx.x >> 6;
  const int wm = wave >> 1, wn = wave & 1;
  const int rsub8 = lane >> 3;
  const int ksub8 = (lane & 7) * 8;

  const unsigned short* Abase = Hbuf + tileM * HID;
  const unsigned short* Bbase = W2t + ((size_t)e * DIM + n0) * HID;

  floatx4 zero = {0.f, 0.f, 0.f, 0.f};
  floatx4 acc[4][2];
#pragma unroll
  for (int i = 0; i < 4; ++i)
#pragma unroll
    for (int j = 0; j < 2; ++j) acc[i][j] = zero;

  for (int k0 = 0; k0 < HID; k0 += 64) {
#pragma unroll
    for (int t = 0; t < 4; ++t) {
      const int c = wave * 4 + t;
      const int row = c * 8 + rsub8;
      async_cp16(&As[c * 512], Abase + (size_t)row * HID + k0 + ksub8);
    }
#pragma unroll
    for (int t = 0; t < 2; ++t) {
      const int c = wave * 2 + t;
      const int row = c * 8 + rsub8;
      async_cp16(&Bs[c * 512], Bbase + (size_t)row * HID + k0 + ksub8);
    }
    __syncthreads();
#pragma unroll
    for (int s = 0; s < 2; ++s) {
      bf16x8 a[4], b[2];
      const int ko = s * 32 + (lane >> 4) * 8;
#pragma unroll
      for (int i = 0; i < 4; ++i)
        a[i] = *(const bf16x8*)&As[(wm * 64 + i * 16 + (lane & 15)) * 64 + ko];
#pragma unroll
      for (int j = 0; j < 2; ++j)
        b[j] = *(const bf16x8*)&Bs[(wn * 32 + j * 16 + (lane & 15)) * 64 + ko];
#pragma unroll
      for (int i = 0; i < 4; ++i)
#pragma unroll
        for (int j = 0; j < 2; ++j)
          acc[i][j] = __builtin_amdgcn_mfma_f32_16x16x32_bf16(a[i], b[j], acc[i][j], 0, 0, 0);
    }
    __syncthreads();
  }

  const int r0 = (lane >> 4) * 4;
  const int cc = lane & 15;
#pragma unroll
  for (int i = 0; i < 4; ++i)
#pragma unroll
    for (int r = 0; r < 4; ++r) {
      const int lrow = tileRow * 128 + wm * 64 + i * 16 + r0 + r;
      if (lrow < cnt) {
        unsigned short* yrow = Y + (size_t)(off + lrow) * DIM + n0 + wn * 32 + cc;
#pragma unroll
        for (int j = 0; j < 2; ++j)
          yrow[j * 16] = f2bf(acc[i][j][r]);
      }
    }
}

// ---------------- combine: out[t] = w0*Y[p0] + w1*Y[p1] --------------------
__global__ __launch_bounds__(256) void moe_combine(
    const unsigned short* __restrict__ Y, const int* __restrict__ inv,
    const float* __restrict__ meta_w, float* __restrict__ out) {
  const int t = blockIdx.x;
  const int p0 = inv[t * 2 + 0], p1 = inv[t * 2 + 1];
  const float w0 = meta_w[t * 2 + 0], w1 = meta_w[t * 2 + 1];
  const ushort4 a = ((const ushort4*)(Y + (size_t)p0 * DIM))[threadIdx.x];
  const ushort4 b = ((const ushort4*)(Y + (size_t)p1 * DIM))[threadIdx.x];
  float4 o;
  o.x = w0 * bf2f(a.x) + w1 * bf2f(b.x);
  o.y = w0 * bf2f(a.y) + w1 * bf2f(b.y);
  o.z = w0 * bf2f(a.z) + w1 * bf2f(b.z);
  o.w = w0 * bf2f(a.w) + w1 * bf2f(b.w);
  ((float4*)(out + (size_t)t * DIM))[threadIdx.x] = o;
}

// ---------------------------------------------------------------------------
extern "C" void kernel_launch(void* const* d_in, const int* in_sizes, int n_in,
                              void* d_out, int out_size, void* d_ws, size_t ws_size,
                              hipStream_t stream) {
  const float* x  = (const float*)d_in[0];
  const float* Wr = (const float*)d_in[1];
  const float* W1 = (const float*)d_in[2];
  const float* W2 = (const float*)d_in[3];
  const float* W3 = (const float*)d_in[4];
  float* out = (float*)d_out;

  char* p = (char*)d_ws;
  auto carve = [&](size_t bytes) { char* r = p; p += (bytes + 255) & ~(size_t)255; return r; };

  int*            hdr    = (int*)carve(256);
  int*            meta_e = (int*)carve((size_t)NTOK * 2 * sizeof(int));
  float*          meta_w = (float*)carve((size_t)NTOK * 2 * sizeof(float));
  int*            tok    = (int*)carve((size_t)NPOS * sizeof(int));
  int*            inv    = (int*)carve((size_t)NTOK * 2 * sizeof(int));
  unsigned short* Xg     = (unsigned short*)carve((size_t)(NPOS + PADR) * DIM * 2);
  unsigned short* Hbuf   = (unsigned short*)carve((size_t)(NPOS + PADR) * HID * 2);
  unsigned short* W1t    = (unsigned short*)carve((size_t)NEXP * HID * DIM * 2);
  unsigned short* W3t    = (unsigned short*)carve((size_t)NEXP * HID * DIM * 2);
  unsigned short* W2t    = (unsigned short*)carve((size_t)NEXP * DIM * HID * 2);
  unsigned short* Y      = Xg;  // Xg is dead after gemm1; reuse as Y buffer

  hipMemsetAsync(hdr, 0, 256, stream);

  moe_router<<<NTOK / 4, 256, 0, stream>>>(x, Wr, meta_e, meta_w);
  moe_hist<<<NPOS / 256, 256, 0, stream>>>(meta_e, hdr);
  moe_build<<<NPOS / 256, 256, 0, stream>>>(meta_e, hdr, tok, inv);
  moe_gather<<<NPOS, 256, 0, stream>>>(x, tok, Xg);

  // W1 [E][1024][1536] -> W1t [E][1536][1024]; same for W3; W2 -> [E][1024][1536]
  moe_transpose_all<<<dim3(384, 1, 24), dim3(256), 0, stream>>>(W1, W3, W2, W1t, W3t, W2t);

  // worst case one expert holds all 8192 tokens -> 64 row tiles
  moe_gemm1<<<dim3(64 * (HID / 64), NEXP), 256, 0, stream>>>(Xg, W1t, W3t, Hbuf, hdr);
  moe_gemm2<<<dim3(64 * (DIM / 64), NEXP), 256, 0, stream>>>(Hbuf, W2t, hdr, Y);
  moe_combine<<<NTOK, 256, 0, stream>>>(Y, inv, meta_w, out);
}

// Round 5
// 550.667 us; speedup vs baseline: 1.0664x; 1.0664x over previous
//
#include <hip/hip_runtime.h>
#include <hip/hip_bf16.h>
#include <math.h>

#define DIM   1024
#define NEXP  8
#define HID   1536
#define NTOK  8192
#define NPOS  16384   // NTOK * TOP_K
#define PADR  128     // padding rows for tile overrun reads

typedef __attribute__((ext_vector_type(8))) short bf16x8;
typedef __attribute__((ext_vector_type(4))) float floatx4;

__device__ __forceinline__ unsigned short f2bf(float f) {
  unsigned int u = __float_as_uint(f);
  u += 0x7FFFu + ((u >> 16) & 1u);   // round-to-nearest-even
  return (unsigned short)(u >> 16);
}

__device__ __forceinline__ float bf2f(unsigned short h) {
  return __uint_as_float((unsigned int)h << 16);
}

__device__ __forceinline__ void async_cp16(void* lds, const void* g) {
  __builtin_amdgcn_global_load_lds(
      (const __attribute__((address_space(1))) unsigned int*)g,
      (__attribute__((address_space(3))) unsigned int*)lds, 16, 0, 0);
}

// count + exclusive-prefix offset for expert e, from hdr[0..7]
__device__ __forceinline__ int2 cnt_off(const int* __restrict__ hdr, int e) {
  int s = 0, c = 0;
#pragma unroll
  for (int i = 0; i < NEXP; ++i) {
    const int v = hdr[i];
    if (i < e) s += v;
    if (i == e) c = v;
  }
  return make_int2(c, s);
}

// ---------------- router: logits, top-2, softmax (no atomics) --------------
__global__ __launch_bounds__(256) void moe_router(
    const float* __restrict__ x, const float* __restrict__ Wr,
    int* __restrict__ meta_e, float* __restrict__ meta_w) {
  const int wave = threadIdx.x >> 6, lane = threadIdx.x & 63;
  const int token = blockIdx.x * 4 + wave;
  const float* xr = x + (size_t)token * DIM;
  float acc[NEXP];
#pragma unroll
  for (int e = 0; e < NEXP; ++e) acc[e] = 0.f;
  for (int i = lane; i < DIM; i += 64) {
    const float xv = xr[i];
    const float* wr = Wr + (size_t)i * NEXP;
#pragma unroll
    for (int e = 0; e < NEXP; ++e) acc[e] += xv * wr[e];
  }
#pragma unroll
  for (int off = 32; off > 0; off >>= 1) {
#pragma unroll
    for (int e = 0; e < NEXP; ++e) acc[e] += __shfl_down(acc[e], off);
  }
  if (lane == 0) {
    int i0 = 0; float v0 = acc[0];
#pragma unroll
    for (int e = 1; e < NEXP; ++e) if (acc[e] > v0) { v0 = acc[e]; i0 = e; }
    int i1 = -1; float v1 = -3.4e38f;
#pragma unroll
    for (int e = 0; e < NEXP; ++e) if (e != i0 && acc[e] > v1) { v1 = acc[e]; i1 = e; }
    const float w0 = 1.f / (1.f + expf(v1 - v0));  // stable softmax over top-2
    meta_e[token * 2 + 0] = i0;
    meta_e[token * 2 + 1] = i1;
    meta_w[token * 2 + 0] = w0;
    meta_w[token * 2 + 1] = 1.f - w0;
  }
}

// ------------- histogram: wave-aggregated counts into hdr[0..7] ------------
__global__ __launch_bounds__(256) void moe_hist(
    const int* __restrict__ meta_e, int* __restrict__ hdr) {
  const int idx = blockIdx.x * 256 + threadIdx.x;  // over NPOS entries
  const int lane = threadIdx.x & 63;
  const int e = meta_e[idx];
#pragma unroll
  for (int ex = 0; ex < NEXP; ++ex) {
    const unsigned long long m = __ballot(e == ex);
    if (m && lane == 0) atomicAdd(&hdr[ex], __popcll(m));
  }
}

// -------- build permutation + inverse map, wave-aggregated cursors ---------
// hdr[16..23] = cursors
__global__ __launch_bounds__(256) void moe_build(
    const int* __restrict__ meta_e, int* __restrict__ hdr,
    int* __restrict__ tok, int* __restrict__ inv) {
  const int idx = blockIdx.x * 256 + threadIdx.x;  // over NPOS entries
  const int lane = threadIdx.x & 63;
  const int token = idx >> 1;
  const int e = meta_e[idx];
  int pos = 0;
#pragma unroll
  for (int ex = 0; ex < NEXP; ++ex) {
    const unsigned long long m = __ballot(e == ex);
    if (m) {
      const int leader = (int)__ffsll((long long)m) - 1;
      int base = 0;
      if (lane == leader) base = atomicAdd(&hdr[16 + ex], __popcll(m));
      base = __shfl(base, leader);
      if (e == ex) {
        const int2 co = cnt_off(hdr, ex);
        pos = co.y + base + (int)__popcll(m & ((1ull << lane) - 1ull));
      }
    }
  }
  tok[pos] = token;
  inv[idx] = pos;
}

// ---------------- gather x rows into bf16, expert-grouped ------------------
__global__ __launch_bounds__(256) void moe_gather(
    const float* __restrict__ x, const int* __restrict__ tok,
    unsigned short* __restrict__ Xg) {
  const int pos = blockIdx.x;
  const int t = tok[pos];
  const float4 v = ((const float4*)(x + (size_t)t * DIM))[threadIdx.x];
  ushort4 o = make_ushort4(f2bf(v.x), f2bf(v.y), f2bf(v.z), f2bf(v.w));
  ((ushort4*)(Xg + (size_t)pos * DIM))[threadIdx.x] = o;
}

// ---------- fused fp32 [E][R][C] -> bf16 [E][C][R] transpose (all 3) -------
// 64x64 tiles: float4 loads, ushort4 stores.
__global__ __launch_bounds__(256) void moe_transpose_all(
    const float* __restrict__ W1, const float* __restrict__ W3,
    const float* __restrict__ W2,
    unsigned short* __restrict__ W1t, unsigned short* __restrict__ W3t,
    unsigned short* __restrict__ W2t) {
  __shared__ float tile[64][65];
  const int z = blockIdx.z;
  const int which = z >> 3, e = z & 7;
  const float* src; unsigned short* dst; int R, C;
  if (which == 0)      { src = W1; dst = W1t; R = DIM; C = HID; }
  else if (which == 1) { src = W3; dst = W3t; R = DIM; C = HID; }
  else                 { src = W2; dst = W2t; R = HID; C = DIM; }
  const int nbx = C / 64;
  const int bx = blockIdx.x % nbx, by = blockIdx.x / nbx;
  const float* ein = src + (size_t)e * R * C;
  unsigned short* eout = dst + (size_t)e * R * C;
  const int c0 = bx * 64, r0 = by * 64;
  const int lx = threadIdx.x & 15, ly = threadIdx.x >> 4;
#pragma unroll
  for (int it = 0; it < 4; ++it) {
    const int r = ly + it * 16;
    const float4 v = *(const float4*)&ein[(size_t)(r0 + r) * C + c0 + lx * 4];
    tile[r][lx * 4 + 0] = v.x;
    tile[r][lx * 4 + 1] = v.y;
    tile[r][lx * 4 + 2] = v.z;
    tile[r][lx * 4 + 3] = v.w;
  }
  __syncthreads();
#pragma unroll
  for (int it = 0; it < 4; ++it) {
    const int cc = ly + it * 16;
    ushort4 o = make_ushort4(f2bf(tile[lx * 4 + 0][cc]), f2bf(tile[lx * 4 + 1][cc]),
                             f2bf(tile[lx * 4 + 2][cc]), f2bf(tile[lx * 4 + 3][cc]));
    *(ushort4*)&eout[(size_t)(c0 + cc) * R + r0 + lx * 4] = o;
  }
}

// XOR-swizzled LDS layout (BK=32, 64 B rows):
//   logical (row, kg) [kg = 16B k-group 0..3] stored at row*64B + (kg ^ ((row>>1)&3))*16B.
//   Staged via global_load_lds lane->base+lane*16: lane holds (row=lane>>2, slot=lane&3),
//   so it must FETCH global kg = (lane&3) ^ ((lane>>3)&3).
//   Fragment read slot for quarter q=(lane>>4): q ^ ((lane>>1)&3) -> rows mod 8 cover all
//   32 banks, 2 lanes/bank (free per m136).

// ---------------- GEMM1: Hbuf = silu(Xg@W1) * (Xg@W3), grouped -------------
// 128x64 tile, BK=32, dual-B fused. 4 waves as 2x2; wave tile 64x32 per mat.
__global__ __launch_bounds__(256) void moe_gemm1(
    const unsigned short* __restrict__ Xg,
    const unsigned short* __restrict__ W1t,
    const unsigned short* __restrict__ W3t,
    unsigned short* __restrict__ Hbuf,
    const int* __restrict__ hdr) {
  const int e = blockIdx.y;
  const int NT = HID / 64;  // 24
  const int tileRow = blockIdx.x / NT;
  const int tileN = blockIdx.x % NT;
  const int2 co = cnt_off(hdr, e);
  const int cnt = co.x;
  if (tileRow * 128 >= cnt) return;
  const int off = co.y;
  const size_t tileM = (size_t)off + (size_t)tileRow * 128;
  const int n0 = tileN * 64;

  __shared__ unsigned short As[128 * 32];   // 8 KB
  __shared__ unsigned short B1s[64 * 32];   // 4 KB
  __shared__ unsigned short B3s[64 * 32];   // 4 KB

  const int lane = threadIdx.x & 63;
  const int wave = threadIdx.x >> 6;
  const int wm = wave >> 1, wn = wave & 1;
  const int rsub = lane >> 2;                               // staging row in 16-row chunk
  const int ksw  = (((lane & 3) ^ ((lane >> 3) & 3))) * 8;  // swizzled k-short offset
  const int kf   = (((lane >> 4) ^ ((lane >> 1) & 3))) * 8; // fragment k-short offset

  const unsigned short* Abase = Xg + tileM * DIM;
  const unsigned short* B1base = W1t + ((size_t)e * HID + n0) * DIM;
  const unsigned short* B3base = W3t + ((size_t)e * HID + n0) * DIM;

  floatx4 zero = {0.f, 0.f, 0.f, 0.f};
  floatx4 acc_h[4][2], acc_g[4][2];
#pragma unroll
  for (int i = 0; i < 4; ++i)
#pragma unroll
    for (int j = 0; j < 2; ++j) { acc_h[i][j] = zero; acc_g[i][j] = zero; }

  for (int k0 = 0; k0 < DIM; k0 += 32) {
    {
      // A: 8 chunks of 16 rows; chunks wave*2, wave*2+1
#pragma unroll
      for (int t = 0; t < 2; ++t) {
        const int c = wave * 2 + t;
        const int row = c * 16 + rsub;
        async_cp16(&As[c * 512], Abase + (size_t)row * DIM + k0 + ksw);
      }
      // B1/B3: 4 chunks of 16 rows; chunk = wave
      const int row = wave * 16 + rsub;
      async_cp16(&B1s[wave * 512], B1base + (size_t)row * DIM + k0 + ksw);
      async_cp16(&B3s[wave * 512], B3base + (size_t)row * DIM + k0 + ksw);
    }
    __syncthreads();
    bf16x8 a[4], b1[2], b3[2];
#pragma unroll
    for (int i = 0; i < 4; ++i)
      a[i] = *(const bf16x8*)&As[(wm * 64 + i * 16 + (lane & 15)) * 32 + kf];
#pragma unroll
    for (int j = 0; j < 2; ++j) {
      b1[j] = *(const bf16x8*)&B1s[(wn * 32 + j * 16 + (lane & 15)) * 32 + kf];
      b3[j] = *(const bf16x8*)&B3s[(wn * 32 + j * 16 + (lane & 15)) * 32 + kf];
    }
#pragma unroll
    for (int i = 0; i < 4; ++i)
#pragma unroll
      for (int j = 0; j < 2; ++j) {
        acc_h[i][j] = __builtin_amdgcn_mfma_f32_16x16x32_bf16(a[i], b1[j], acc_h[i][j], 0, 0, 0);
        acc_g[i][j] = __builtin_amdgcn_mfma_f32_16x16x32_bf16(a[i], b3[j], acc_g[i][j], 0, 0, 0);
      }
    __syncthreads();
  }

  // epilogue: silu(h)*g -> bf16, guarded against tile overrun into next expert
  const int r0 = (lane >> 4) * 4;
  const int cc = lane & 15;
#pragma unroll
  for (int i = 0; i < 4; ++i)
#pragma unroll
    for (int r = 0; r < 4; ++r) {
      const int lrow = tileRow * 128 + wm * 64 + i * 16 + r0 + r;
      if (lrow < cnt) {
        unsigned short* hrow = Hbuf + (size_t)(off + lrow) * HID + n0 + wn * 32 + cc;
#pragma unroll
        for (int j = 0; j < 2; ++j) {
          const float h = acc_h[i][j][r];
          const float g = acc_g[i][j][r];
          const float s = h / (1.f + expf(-h));
          hrow[j * 16] = f2bf(s * g);
        }
      }
    }
}

// ---------------- GEMM2: Y[pos] = Hbuf @ W2 (bf16 rows, no atomics) --------
// 128x64 tile, BK=32. A: Hbuf [pos][k] (k=HID). B: W2t [E][n][k] (n over DIM).
__global__ __launch_bounds__(256) void moe_gemm2(
    const unsigned short* __restrict__ Hbuf,
    const unsigned short* __restrict__ W2t,
    const int* __restrict__ hdr,
    unsigned short* __restrict__ Y) {
  const int e = blockIdx.y;
  const int NT = DIM / 64;  // 16
  const int tileRow = blockIdx.x / NT;
  const int tileN = blockIdx.x % NT;
  const int2 co = cnt_off(hdr, e);
  const int cnt = co.x;
  if (tileRow * 128 >= cnt) return;
  const int off = co.y;
  const size_t tileM = (size_t)off + (size_t)tileRow * 128;
  const int n0 = tileN * 64;

  __shared__ unsigned short As[128 * 32];   // 8 KB
  __shared__ unsigned short Bs[64 * 32];    // 4 KB

  const int lane = threadIdx.x & 63;
  const int wave = threadIdx.x >> 6;
  const int wm = wave >> 1, wn = wave & 1;
  const int rsub = lane >> 2;
  const int ksw  = (((lane & 3) ^ ((lane >> 3) & 3))) * 8;
  const int kf   = (((lane >> 4) ^ ((lane >> 1) & 3))) * 8;

  const unsigned short* Abase = Hbuf + tileM * HID;
  const unsigned short* Bbase = W2t + ((size_t)e * DIM + n0) * HID;

  floatx4 zero = {0.f, 0.f, 0.f, 0.f};
  floatx4 acc[4][2];
#pragma unroll
  for (int i = 0; i < 4; ++i)
#pragma unroll
    for (int j = 0; j < 2; ++j) acc[i][j] = zero;

  for (int k0 = 0; k0 < HID; k0 += 32) {
#pragma unroll
    for (int t = 0; t < 2; ++t) {
      const int c = wave * 2 + t;
      const int row = c * 16 + rsub;
      async_cp16(&As[c * 512], Abase + (size_t)row * HID + k0 + ksw);
    }
    {
      const int row = wave * 16 + rsub;
      async_cp16(&Bs[wave * 512], Bbase + (size_t)row * HID + k0 + ksw);
    }
    __syncthreads();
    bf16x8 a[4], b[2];
#pragma unroll
    for (int i = 0; i < 4; ++i)
      a[i] = *(const bf16x8*)&As[(wm * 64 + i * 16 + (lane & 15)) * 32 + kf];
#pragma unroll
    for (int j = 0; j < 2; ++j)
      b[j] = *(const bf16x8*)&Bs[(wn * 32 + j * 16 + (lane & 15)) * 32 + kf];
#pragma unroll
    for (int i = 0; i < 4; ++i)
#pragma unroll
      for (int j = 0; j < 2; ++j)
        acc[i][j] = __builtin_amdgcn_mfma_f32_16x16x32_bf16(a[i], b[j], acc[i][j], 0, 0, 0);
    __syncthreads();
  }

  const int r0 = (lane >> 4) * 4;
  const int cc = lane & 15;
#pragma unroll
  for (int i = 0; i < 4; ++i)
#pragma unroll
    for (int r = 0; r < 4; ++r) {
      const int lrow = tileRow * 128 + wm * 64 + i * 16 + r0 + r;
      if (lrow < cnt) {
        unsigned short* yrow = Y + (size_t)(off + lrow) * DIM + n0 + wn * 32 + cc;
#pragma unroll
        for (int j = 0; j < 2; ++j)
          yrow[j * 16] = f2bf(acc[i][j][r]);
      }
    }
}

// ---------------- combine: out[t] = w0*Y[p0] + w1*Y[p1] --------------------
__global__ __launch_bounds__(256) void moe_combine(
    const unsigned short* __restrict__ Y, const int* __restrict__ inv,
    const float* __restrict__ meta_w, float* __restrict__ out) {
  const int t = blockIdx.x;
  const int p0 = inv[t * 2 + 0], p1 = inv[t * 2 + 1];
  const float w0 = meta_w[t * 2 + 0], w1 = meta_w[t * 2 + 1];
  const ushort4 a = ((const ushort4*)(Y + (size_t)p0 * DIM))[threadIdx.x];
  const ushort4 b = ((const ushort4*)(Y + (size_t)p1 * DIM))[threadIdx.x];
  float4 o;
  o.x = w0 * bf2f(a.x) + w1 * bf2f(b.x);
  o.y = w0 * bf2f(a.y) + w1 * bf2f(b.y);
  o.z = w0 * bf2f(a.z) + w1 * bf2f(b.z);
  o.w = w0 * bf2f(a.w) + w1 * bf2f(b.w);
  ((float4*)(out + (size_t)t * DIM))[threadIdx.x] = o;
}

// ---------------------------------------------------------------------------
extern "C" void kernel_launch(void* const* d_in, const int* in_sizes, int n_in,
                              void* d_out, int out_size, void* d_ws, size_t ws_size,
                              hipStream_t stream) {
  const float* x  = (const float*)d_in[0];
  const float* Wr = (const float*)d_in[1];
  const float* W1 = (const float*)d_in[2];
  const float* W2 = (const float*)d_in[3];
  const float* W3 = (const float*)d_in[4];
  float* out = (float*)d_out;

  char* p = (char*)d_ws;
  auto carve = [&](size_t bytes) { char* r = p; p += (bytes + 255) & ~(size_t)255; return r; };

  int*            hdr    = (int*)carve(256);
  int*            meta_e = (int*)carve((size_t)NTOK * 2 * sizeof(int));
  float*          meta_w = (float*)carve((size_t)NTOK * 2 * sizeof(float));
  int*            tok    = (int*)carve((size_t)NPOS * sizeof(int));
  int*            inv    = (int*)carve((size_t)NTOK * 2 * sizeof(int));
  unsigned short* Xg     = (unsigned short*)carve((size_t)(NPOS + PADR) * DIM * 2);
  unsigned short* Hbuf   = (unsigned short*)carve((size_t)(NPOS + PADR) * HID * 2);
  unsigned short* W1t    = (unsigned short*)carve((size_t)NEXP * HID * DIM * 2);
  unsigned short* W3t    = (unsigned short*)carve((size_t)NEXP * HID * DIM * 2);
  unsigned short* W2t    = (unsigned short*)carve((size_t)NEXP * DIM * HID * 2);
  unsigned short* Y      = Xg;  // Xg is dead after gemm1; reuse as Y buffer

  hipMemsetAsync(hdr, 0, 256, stream);

  moe_router<<<NTOK / 4, 256, 0, stream>>>(x, Wr, meta_e, meta_w);
  moe_hist<<<NPOS / 256, 256, 0, stream>>>(meta_e, hdr);
  moe_build<<<NPOS / 256, 256, 0, stream>>>(meta_e, hdr, tok, inv);
  moe_gather<<<NPOS, 256, 0, stream>>>(x, tok, Xg);

  // W1 [E][1024][1536] -> W1t [E][1536][1024]; same for W3; W2 -> [E][1024][1536]
  moe_transpose_all<<<dim3(384, 1, 24), dim3(256), 0, stream>>>(W1, W3, W2, W1t, W3t, W2t);

  // worst case one expert holds all 8192 tokens -> 64 row tiles
  moe_gemm1<<<dim3(64 * (HID / 64), NEXP), 256, 0, stream>>>(Xg, W1t, W3t, Hbuf, hdr);
  moe_gemm2<<<dim3(64 * (DIM / 64), NEXP), 256, 0, stream>>>(Hbuf, W2t, hdr, Y);
  moe_combine<<<NTOK, 256, 0, stream>>>(Y, inv, meta_w, out);
}